// Round 1
// baseline (1107.823 us; speedup 1.0000x reference)
//
#include <hip/hip_runtime.h>
#include <hip/hip_bf16.h>
#include <math.h>

#define D_MODEL 1024
#define SEQ     2048
#define BATCH   2
#define NHEAD   16
#define DKH     64

// ---------------------------------------------------------------------------
// SGEMM with bias: C = A @ W + b
// A: [M,K] row-major, W: [K,N] row-major, C: [M,N]
// block = 256 threads, tile 128x128, BK=16, per-thread 8x8 micro-tile.
// blockIdx.z selects among 3 (W,b,C) sets so QKV runs as one 768-block grid.
// ---------------------------------------------------------------------------
constexpr int BM = 128, BN = 128, BKK = 16, TM = 8, TN = 8;

__global__ __launch_bounds__(256) void sgemm_bias3(
    const float* __restrict__ A,
    const float* __restrict__ W0, const float* __restrict__ W1, const float* __restrict__ W2,
    const float* __restrict__ b0, const float* __restrict__ b1, const float* __restrict__ b2,
    float* __restrict__ C0, float* __restrict__ C1, float* __restrict__ C2,
    int M, int N, int K)
{
    const float* W; const float* bias; float* C;
    if (blockIdx.z == 0)      { W = W0; bias = b0; C = C0; }
    else if (blockIdx.z == 1) { W = W1; bias = b1; C = C1; }
    else                      { W = W2; bias = b2; C = C2; }

    __shared__ float As[BKK][BM + 4];   // stored transposed: As[k][m]
    __shared__ float Bs[BKK][BN + 4];   // Bs[k][n]

    const int tid  = threadIdx.x;
    const int brow = blockIdx.y * BM;
    const int bcol = blockIdx.x * BN;
    const int tr   = (tid >> 4) * TM;   // 0..120
    const int tc   = (tid & 15) * TN;   // 0..120

    float acc[TM][TN] = {};

    for (int k0 = 0; k0 < K; k0 += BKK) {
        // Load A tile (128x16) and W tile (16x128): 2 float4 each per thread.
        #pragma unroll
        for (int i = 0; i < 2; ++i) {
            int f  = tid + i * 256;          // float4 id 0..511
            int ar = f >> 2;                 // 0..127 (row in A tile)
            int ac = (f & 3) * 4;            // 0..12  (col in A tile)
            float4 av = *reinterpret_cast<const float4*>(&A[(size_t)(brow + ar) * K + k0 + ac]);
            As[ac + 0][ar] = av.x; As[ac + 1][ar] = av.y;
            As[ac + 2][ar] = av.z; As[ac + 3][ar] = av.w;

            int wr = f >> 5;                 // 0..15  (row in W tile)
            int wc = (f & 31) * 4;           // 0..124 (col in W tile)
            float4 wv = *reinterpret_cast<const float4*>(&W[(size_t)(k0 + wr) * N + bcol + wc]);
            *reinterpret_cast<float4*>(&Bs[wr][wc]) = wv;
        }
        __syncthreads();

        #pragma unroll
        for (int kk = 0; kk < BKK; ++kk) {
            float a[TM], b[TN];
            #pragma unroll
            for (int i = 0; i < TM; ++i) a[i] = As[kk][tr + i];
            #pragma unroll
            for (int j = 0; j < TN; ++j) b[j] = Bs[kk][tc + j];
            #pragma unroll
            for (int i = 0; i < TM; ++i)
                #pragma unroll
                for (int j = 0; j < TN; ++j)
                    acc[i][j] = fmaf(a[i], b[j], acc[i][j]);
        }
        __syncthreads();
    }

    #pragma unroll
    for (int i = 0; i < TM; ++i) {
        float* crow = &C[(size_t)(brow + tr + i) * N + bcol + tc];
        #pragma unroll
        for (int j = 0; j < TN; j += 4) {
            float4 v;
            v.x = acc[i][j + 0] + bias[bcol + tc + j + 0];
            v.y = acc[i][j + 1] + bias[bcol + tc + j + 1];
            v.z = acc[i][j + 2] + bias[bcol + tc + j + 2];
            v.w = acc[i][j + 3] + bias[bcol + tc + j + 3];
            *reinterpret_cast<float4*>(&crow[j]) = v;
        }
    }
}

// ---------------------------------------------------------------------------
// Flash attention over contiguous [2048,64] Q/K/V blocks per (b,h).
// grid = (32 q-tiles, 32 bh), block = 256 threads.
// Per block: 64-query tile; loop over 32 K/V tiles of 64 rows.
// Thread micro-tile: 4q x 4k (S phase) / 4q x 4d (O phase).
// Online softmax per q-row across the 16 lanes of its group (shfl_xor).
// LDS = 4 * 64*64*4B = 64 KB exactly.
// ---------------------------------------------------------------------------
__global__ __launch_bounds__(256) void attn_kernel(
    const float* __restrict__ Qg, const float* __restrict__ Kg,
    const float* __restrict__ Vg, float* __restrict__ Og)
{
    constexpr int S = SEQ, D = DKH, QT = 64, KT = 64, LD = 64;
    __shared__ float QsT[D][LD];    // [d][q]
    __shared__ float KsT[D][LD];    // [d][k]
    __shared__ float Vs [KT][LD];   // [k][d]
    __shared__ float PsT[KT][LD];   // [k][q]

    const int tid = threadIdx.x;
    const int bh  = blockIdx.y;     // 0..31 (= b*16 + h)
    const int qt  = blockIdx.x;     // 0..31

    const float* Qb = Qg + (size_t)bh * S * D + (size_t)qt * QT * D;
    const float* Kb = Kg + (size_t)bh * S * D;
    const float* Vb = Vg + (size_t)bh * S * D;

    // Load Q tile (4096 contiguous floats), store transposed into QsT.
    #pragma unroll
    for (int i = 0; i < 4; ++i) {
        int f = tid + i * 256;               // float4 id 0..1023
        float4 v = reinterpret_cast<const float4*>(Qb)[f];
        int r = f >> 4;                      // q row 0..63
        int c = (f & 15) * 4;                // d col
        QsT[c + 0][r] = v.x; QsT[c + 1][r] = v.y;
        QsT[c + 2][r] = v.z; QsT[c + 3][r] = v.w;
    }

    const int q0 = (tid >> 4) * 4;           // this thread's 4 q rows
    const int c0 = (tid & 15) * 4;           // 4 k cols (S phase) / 4 d cols (O phase)

    float o[4][4] = {};
    float m_run[4] = {-1e30f, -1e30f, -1e30f, -1e30f};
    float l_run[4] = {0.f, 0.f, 0.f, 0.f};

    for (int kt = 0; kt < S / KT; ++kt) {
        __syncthreads();                     // prev O-phase reads done; Qs ready (iter 0)
        const float* ksrc = Kb + (size_t)kt * KT * D;
        const float* vsrc = Vb + (size_t)kt * KT * D;
        #pragma unroll
        for (int i = 0; i < 4; ++i) {
            int f = tid + i * 256;
            int r = f >> 4;
            int c = (f & 15) * 4;
            float4 kv = reinterpret_cast<const float4*>(ksrc)[f];
            KsT[c + 0][r] = kv.x; KsT[c + 1][r] = kv.y;
            KsT[c + 2][r] = kv.z; KsT[c + 3][r] = kv.w;
            float4 vv = reinterpret_cast<const float4*>(vsrc)[f];
            *reinterpret_cast<float4*>(&Vs[r][c]) = vv;
        }
        __syncthreads();

        // S = (Q @ K^T) * 0.125 ; outer-product over d
        float s[4][4] = {};
        #pragma unroll 8
        for (int d = 0; d < D; ++d) {
            float4 qv = *reinterpret_cast<const float4*>(&QsT[d][q0]);
            float4 kv = *reinterpret_cast<const float4*>(&KsT[d][c0]);
            float qa[4] = {qv.x, qv.y, qv.z, qv.w};
            float ka[4] = {kv.x, kv.y, kv.z, kv.w};
            #pragma unroll
            for (int i = 0; i < 4; ++i)
                #pragma unroll
                for (int j = 0; j < 4; ++j)
                    s[i][j] = fmaf(qa[i], ka[j], s[i][j]);
        }

        // Online softmax: reduce across the 16 lanes of the q-group.
        float alpha[4];
        #pragma unroll
        for (int i = 0; i < 4; ++i) {
            #pragma unroll
            for (int j = 0; j < 4; ++j) s[i][j] *= 0.125f;
            float mx = fmaxf(fmaxf(s[i][0], s[i][1]), fmaxf(s[i][2], s[i][3]));
            #pragma unroll
            for (int msk = 1; msk < 16; msk <<= 1)
                mx = fmaxf(mx, __shfl_xor(mx, msk, 64));
            float mnew = fmaxf(m_run[i], mx);
            alpha[i] = __expf(m_run[i] - mnew);
            float rs = 0.f;
            #pragma unroll
            for (int j = 0; j < 4; ++j) { s[i][j] = __expf(s[i][j] - mnew); rs += s[i][j]; }
            #pragma unroll
            for (int msk = 1; msk < 16; msk <<= 1)
                rs += __shfl_xor(rs, msk, 64);
            l_run[i] = l_run[i] * alpha[i] + rs;
            m_run[i] = mnew;
        }

        // Stash P transposed for the O phase.
        #pragma unroll
        for (int i = 0; i < 4; ++i)
            #pragma unroll
            for (int j = 0; j < 4; ++j)
                PsT[c0 + j][q0 + i] = s[i][j];
        __syncthreads();

        // O = diag(alpha) * O + P @ V ; outer-product over k
        #pragma unroll
        for (int i = 0; i < 4; ++i) {
            o[i][0] *= alpha[i]; o[i][1] *= alpha[i];
            o[i][2] *= alpha[i]; o[i][3] *= alpha[i];
        }
        #pragma unroll 8
        for (int k = 0; k < KT; ++k) {
            float4 pv = *reinterpret_cast<const float4*>(&PsT[k][q0]);
            float4 vv = *reinterpret_cast<const float4*>(&Vs[k][c0]);
            float pa[4] = {pv.x, pv.y, pv.z, pv.w};
            float va[4] = {vv.x, vv.y, vv.z, vv.w};
            #pragma unroll
            for (int i = 0; i < 4; ++i)
                #pragma unroll
                for (int j = 0; j < 4; ++j)
                    o[i][j] = fmaf(pa[i], va[j], o[i][j]);
        }
    }

    // Epilogue: normalize and store ctx (same contiguous per-(b,h) layout).
    float* Ob = Og + (size_t)bh * S * D + (size_t)qt * QT * D;
    #pragma unroll
    for (int i = 0; i < 4; ++i) {
        float inv = 1.0f / l_run[i];
        float4 v;
        v.x = o[i][0] * inv; v.y = o[i][1] * inv;
        v.z = o[i][2] * inv; v.w = o[i][3] * inv;
        *reinterpret_cast<float4*>(&Ob[(q0 + i) * D + c0]) = v;
    }
}

// ---------------------------------------------------------------------------
extern "C" void kernel_launch(void* const* d_in, const int* in_sizes, int n_in,
                              void* d_out, int out_size, void* d_ws, size_t ws_size,
                              hipStream_t stream)
{
    const float* x  = (const float*)d_in[0];
    const float* Wq = (const float*)d_in[1];
    const float* bq = (const float*)d_in[2];
    const float* Wk = (const float*)d_in[3];
    const float* bk = (const float*)d_in[4];
    const float* Wv = (const float*)d_in[5];
    const float* bv = (const float*)d_in[6];
    const float* Wo = (const float*)d_in[7];
    const float* bo = (const float*)d_in[8];
    float* out = (float*)d_out;

    const int M = BATCH * SEQ;     // 4096
    const int N = D_MODEL;         // 1024
    const int K = D_MODEL;         // 1024

    float* ws  = (float*)d_ws;
    float* Q   = ws;
    float* Km  = ws + (size_t)M * N;
    float* Vm  = ws + 2 * (size_t)M * N;
    float* ctx = ws + 3 * (size_t)M * N;

    dim3 blk(256);

    // QKV projections (one grid, z selects q/k/v)
    sgemm_bias3<<<dim3(N / BN, M / BM, 3), blk, 0, stream>>>(
        x, Wq, Wk, Wv, bq, bk, bv, Q, Km, Vm, M, N, K);

    // Attention per (b,h) on contiguous [2048,64] blocks
    attn_kernel<<<dim3(SEQ / 64, BATCH * NHEAD), blk, 0, stream>>>(Q, Km, Vm, ctx);

    // Output projection
    sgemm_bias3<<<dim3(N / BN, M / BM, 1), blk, 0, stream>>>(
        ctx, Wo, Wo, Wo, bo, bo, bo, out, out, out, M, N, K);
}

// Round 2
// 659.023 us; speedup vs baseline: 1.6810x; 1.6810x over previous
//
#include <hip/hip_runtime.h>
#include <hip/hip_bf16.h>
#include <math.h>

#define D_MODEL 1024
#define SEQ     2048
#define BATCH   2
#define NHEAD   16
#define DKH     64
#define BH      (BATCH * NHEAD)   // 32

typedef unsigned short u16;
typedef unsigned int   u32;
typedef __bf16 bf16x8 __attribute__((ext_vector_type(8)));
typedef float  f32x4  __attribute__((ext_vector_type(4)));

#define MFMA16(a, b, c) __builtin_amdgcn_mfma_f32_16x16x32_bf16((a), (b), (c), 0, 0, 0)

__device__ __forceinline__ u16 f2bf(float x) {
    u32 u = __float_as_uint(x);
    u += 0x7fffu + ((u >> 16) & 1u);   // RNE (finite data; no NaN handling needed)
    return (u16)(u >> 16);
}
__device__ __forceinline__ float bf2f(u16 b) {
    return __uint_as_float(((u32)b) << 16);
}

// ---------------------------------------------------------------------------
// fp32 SGEMM with bias (unchanged from round 0): C = A @ W + b
// ---------------------------------------------------------------------------
constexpr int BM = 128, BN = 128, BKK = 16, TM = 8, TN = 8;

__global__ __launch_bounds__(256) void sgemm_bias3(
    const float* __restrict__ A,
    const float* __restrict__ W0, const float* __restrict__ W1, const float* __restrict__ W2,
    const float* __restrict__ b0, const float* __restrict__ b1, const float* __restrict__ b2,
    float* __restrict__ C0, float* __restrict__ C1, float* __restrict__ C2,
    int M, int N, int K)
{
    const float* W; const float* bias; float* C;
    if (blockIdx.z == 0)      { W = W0; bias = b0; C = C0; }
    else if (blockIdx.z == 1) { W = W1; bias = b1; C = C1; }
    else                      { W = W2; bias = b2; C = C2; }

    __shared__ float As[BKK][BM + 4];
    __shared__ float Bs[BKK][BN + 4];

    const int tid  = threadIdx.x;
    const int brow = blockIdx.y * BM;
    const int bcol = blockIdx.x * BN;
    const int tr   = (tid >> 4) * TM;
    const int tc   = (tid & 15) * TN;

    float acc[TM][TN] = {};

    for (int k0 = 0; k0 < K; k0 += BKK) {
        #pragma unroll
        for (int i = 0; i < 2; ++i) {
            int f  = tid + i * 256;
            int ar = f >> 2;
            int ac = (f & 3) * 4;
            float4 av = *reinterpret_cast<const float4*>(&A[(size_t)(brow + ar) * K + k0 + ac]);
            As[ac + 0][ar] = av.x; As[ac + 1][ar] = av.y;
            As[ac + 2][ar] = av.z; As[ac + 3][ar] = av.w;

            int wr = f >> 5;
            int wc = (f & 31) * 4;
            float4 wv = *reinterpret_cast<const float4*>(&W[(size_t)(k0 + wr) * N + bcol + wc]);
            *reinterpret_cast<float4*>(&Bs[wr][wc]) = wv;
        }
        __syncthreads();

        #pragma unroll
        for (int kk = 0; kk < BKK; ++kk) {
            float a[TM], b[TN];
            #pragma unroll
            for (int i = 0; i < TM; ++i) a[i] = As[kk][tr + i];
            #pragma unroll
            for (int j = 0; j < TN; ++j) b[j] = Bs[kk][tc + j];
            #pragma unroll
            for (int i = 0; i < TM; ++i)
                #pragma unroll
                for (int j = 0; j < TN; ++j)
                    acc[i][j] = fmaf(a[i], b[j], acc[i][j]);
        }
        __syncthreads();
    }

    #pragma unroll
    for (int i = 0; i < TM; ++i) {
        float* crow = &C[(size_t)(brow + tr + i) * N + bcol + tc];
        #pragma unroll
        for (int j = 0; j < TN; j += 4) {
            float4 v;
            v.x = acc[i][j + 0] + bias[bcol + tc + j + 0];
            v.y = acc[i][j + 1] + bias[bcol + tc + j + 1];
            v.z = acc[i][j + 2] + bias[bcol + tc + j + 2];
            v.w = acc[i][j + 3] + bias[bcol + tc + j + 3];
            *reinterpret_cast<float4*>(&crow[j]) = v;
        }
    }
}

// ---------------------------------------------------------------------------
// fp32 -> split bf16 (hi + lo) elementwise
// ---------------------------------------------------------------------------
__global__ __launch_bounds__(256) void hilo_conv(
    const float* __restrict__ src, u16* __restrict__ hi, u16* __restrict__ lo, int n4)
{
    int i = blockIdx.x * 256 + threadIdx.x;
    if (i >= n4) return;
    float4 v = reinterpret_cast<const float4*>(src)[i];
    float a[4] = {v.x, v.y, v.z, v.w};
    u16 hh[4], ll[4];
    #pragma unroll
    for (int j = 0; j < 4; ++j) {
        u16 hb = f2bf(a[j]);
        hh[j] = hb;
        ll[j] = f2bf(a[j] - bf2f(hb));
    }
    uint2 H, L;
    H.x = hh[0] | ((u32)hh[1] << 16); H.y = hh[2] | ((u32)hh[3] << 16);
    L.x = ll[0] | ((u32)ll[1] << 16); L.y = ll[2] | ((u32)ll[3] << 16);
    reinterpret_cast<uint2*>(hi)[i] = H;
    reinterpret_cast<uint2*>(lo)[i] = L;
}

// ---------------------------------------------------------------------------
// V fp32 [BH][SEQ][64] -> Vt bf16 [BH][64][SEQ] (transposed per head-block)
// ---------------------------------------------------------------------------
__global__ __launch_bounds__(256) void v_transpose(
    const float* __restrict__ V, u16* __restrict__ Vt)
{
    __shared__ u16 T[64][72];
    const int bh = blockIdx.y, st = blockIdx.x;   // st: 64-row s-tile, 0..31
    const float* src = V + ((size_t)bh * SEQ + (size_t)st * 64) * 64;
    const int t = threadIdx.x;
    #pragma unroll
    for (int i = 0; i < 4; ++i) {
        int c  = t + i * 256;          // 0..1023 float4 chunks
        int s  = c >> 4;               // 0..63
        int d0 = (c & 15) * 4;
        float4 v = reinterpret_cast<const float4*>(src)[c];
        T[d0 + 0][s] = f2bf(v.x);
        T[d0 + 1][s] = f2bf(v.y);
        T[d0 + 2][s] = f2bf(v.z);
        T[d0 + 3][s] = f2bf(v.w);
    }
    __syncthreads();
    const int d = t >> 2, seg = t & 3;
    u16* dst = Vt + (size_t)bh * 64 * SEQ + (size_t)d * SEQ + st * 64 + seg * 16;
    uint4 a = *reinterpret_cast<const uint4*>(&T[d][seg * 16]);
    uint4 b = *reinterpret_cast<const uint4*>(&T[d][seg * 16 + 8]);
    reinterpret_cast<uint4*>(dst)[0] = a;
    reinterpret_cast<uint4*>(dst)[1] = b;
}

// ---------------------------------------------------------------------------
// MFMA flash attention.
// grid = (16 q-tiles of 128, 32 bh), block = 256 (4 waves).
// Wave w owns q-rows [w*32, w*32+32). Split-bf16 QK^T, bf16 PV.
// LDS: Kh/Kl/Vt [64][72], Pb [128][72], Qh/Ql [128][64]  = 78,848 B -> 2 blk/CU
// ---------------------------------------------------------------------------
__global__ __launch_bounds__(256, 2) void attn_mfma(
    const u16* __restrict__ Qh_g, const u16* __restrict__ Ql_g,
    const u16* __restrict__ Kh_g, const u16* __restrict__ Kl_g,
    const u16* __restrict__ Vt_g, float* __restrict__ Og)
{
    __shared__ u16 Kh[64 * 72];
    __shared__ u16 Kl[64 * 72];
    __shared__ u16 Vt[64 * 72];
    __shared__ u16 Pb[128 * 72];
    __shared__ u16 Qh[128 * 64];
    __shared__ u16 Ql[128 * 64];

    const int tid  = threadIdx.x;
    const int wv   = tid >> 6;
    const int lane = tid & 63;
    const int quad = lane >> 4;
    const int l16  = lane & 15;
    const int bh   = blockIdx.y;
    const int qt   = blockIdx.x;

    // ---- stage Q tile (flat 16 KB copies) ----
    const size_t qbase = ((size_t)bh * SEQ + (size_t)qt * 128) * 64;
    {
        const uint4* sH = reinterpret_cast<const uint4*>(Qh_g + qbase);
        const uint4* sL = reinterpret_cast<const uint4*>(Ql_g + qbase);
        uint4* dH = reinterpret_cast<uint4*>(Qh);
        uint4* dL = reinterpret_cast<uint4*>(Ql);
        #pragma unroll
        for (int i = 0; i < 4; ++i) {
            dH[tid + i * 256] = sH[tid + i * 256];
            dL[tid + i * 256] = sL[tid + i * 256];
        }
    }
    __syncthreads();

    // ---- persistent Q fragments ----
    bf16x8 qf[2][2][2];   // [sub][kstep][hi/lo]
    #pragma unroll
    for (int sub = 0; sub < 2; ++sub)
        #pragma unroll
        for (int ks = 0; ks < 2; ++ks) {
            int off = (wv * 32 + sub * 16 + l16) * 64 + ks * 32 + quad * 8;
            qf[sub][ks][0] = *reinterpret_cast<const bf16x8*>(&Qh[off]);
            qf[sub][ks][1] = *reinterpret_cast<const bf16x8*>(&Ql[off]);
        }

    f32x4 oacc[2][4] = {};
    float m_run[2][4], l_run[2][4];
    #pragma unroll
    for (int s = 0; s < 2; ++s)
        #pragma unroll
        for (int r = 0; r < 4; ++r) { m_run[s][r] = -1e30f; l_run[s][r] = 0.f; }

    const size_t kbh  = (size_t)bh * SEQ * 64;
    const size_t vtbh = (size_t)bh * 64 * SEQ;

    for (int kt = 0; kt < SEQ / 64; ++kt) {
        __syncthreads();   // previous iteration's K/V reads complete
        // ---- stage K (hi/lo) and Vt tiles, padded rows (72 u16) ----
        {
            const size_t kof = kbh + (size_t)kt * 64 * 64;
            #pragma unroll
            for (int i = 0; i < 2; ++i) {
                int c = tid + i * 256;       // 0..511 16B chunks
                int row = c >> 3, seg = c & 7;
                *reinterpret_cast<uint4*>(&Kh[row * 72 + seg * 8]) =
                    *reinterpret_cast<const uint4*>(&Kh_g[kof + (size_t)c * 8]);
                *reinterpret_cast<uint4*>(&Kl[row * 72 + seg * 8]) =
                    *reinterpret_cast<const uint4*>(&Kl_g[kof + (size_t)c * 8]);
                *reinterpret_cast<uint4*>(&Vt[row * 72 + seg * 8]) =
                    *reinterpret_cast<const uint4*>(&Vt_g[vtbh + (size_t)row * SEQ + kt * 64 + seg * 8]);
            }
        }
        __syncthreads();

        // ---- S = (Q K^T) * 0.125, split-bf16 ----
        f32x4 sacc[2][4] = {};   // [sub][ktile16]
        #pragma unroll
        for (int t4 = 0; t4 < 4; ++t4) {
            bf16x8 kh[2], kl[2];
            #pragma unroll
            for (int ks = 0; ks < 2; ++ks) {
                int off = (t4 * 16 + l16) * 72 + ks * 32 + quad * 8;
                kh[ks] = *reinterpret_cast<const bf16x8*>(&Kh[off]);
                kl[ks] = *reinterpret_cast<const bf16x8*>(&Kl[off]);
            }
            #pragma unroll
            for (int sub = 0; sub < 2; ++sub) {
                f32x4 a = sacc[sub][t4];
                #pragma unroll
                for (int ks = 0; ks < 2; ++ks) {
                    a = MFMA16(qf[sub][ks][0], kh[ks], a);
                    a = MFMA16(qf[sub][ks][0], kl[ks], a);
                    a = MFMA16(qf[sub][ks][1], kh[ks], a);
                }
                sacc[sub][t4] = a;
            }
        }

        // ---- online softmax (C-layout; rows live in 16-lane quads) ----
        #pragma unroll
        for (int sub = 0; sub < 2; ++sub) {
            #pragma unroll
            for (int t4 = 0; t4 < 4; ++t4) sacc[sub][t4] *= 0.125f;
            #pragma unroll
            for (int r = 0; r < 4; ++r) {
                float s0 = sacc[sub][0][r], s1 = sacc[sub][1][r];
                float s2 = sacc[sub][2][r], s3 = sacc[sub][3][r];
                float mx = fmaxf(fmaxf(s0, s1), fmaxf(s2, s3));
                #pragma unroll
                for (int m = 1; m < 16; m <<= 1) mx = fmaxf(mx, __shfl_xor(mx, m, 64));
                float mnew  = fmaxf(m_run[sub][r], mx);
                float alpha = __expf(m_run[sub][r] - mnew);
                m_run[sub][r] = mnew;
                float p0 = __expf(s0 - mnew), p1 = __expf(s1 - mnew);
                float p2 = __expf(s2 - mnew), p3 = __expf(s3 - mnew);
                float rs = (p0 + p1) + (p2 + p3);
                #pragma unroll
                for (int m = 1; m < 16; m <<= 1) rs += __shfl_xor(rs, m, 64);
                l_run[sub][r] = l_run[sub][r] * alpha + rs;
                int row = wv * 32 + sub * 16 + quad * 4 + r;
                Pb[row * 72 +  0 + l16] = f2bf(p0);
                Pb[row * 72 + 16 + l16] = f2bf(p1);
                Pb[row * 72 + 32 + l16] = f2bf(p2);
                Pb[row * 72 + 48 + l16] = f2bf(p3);
                #pragma unroll
                for (int dt = 0; dt < 4; ++dt) oacc[sub][dt][r] *= alpha;
            }
        }
        // Pb region is wave-private (rows wv*32..+31): no barrier, lgkmcnt only.

        // ---- O += P @ V ----
        #pragma unroll
        for (int sub = 0; sub < 2; ++sub) {
            bf16x8 ap[2];
            #pragma unroll
            for (int ks = 0; ks < 2; ++ks)
                ap[ks] = *reinterpret_cast<const bf16x8*>(
                    &Pb[(wv * 32 + sub * 16 + l16) * 72 + ks * 32 + quad * 8]);
            #pragma unroll
            for (int dt = 0; dt < 4; ++dt) {
                #pragma unroll
                for (int ks = 0; ks < 2; ++ks) {
                    bf16x8 bv = *reinterpret_cast<const bf16x8*>(
                        &Vt[(dt * 16 + l16) * 72 + ks * 32 + quad * 8]);
                    oacc[sub][dt] = MFMA16(ap[ks], bv, oacc[sub][dt]);
                }
            }
        }
    }

    // ---- epilogue: normalize, store ctx ----
    float* Ob = Og + ((size_t)bh * SEQ + (size_t)qt * 128) * 64;
    #pragma unroll
    for (int sub = 0; sub < 2; ++sub) {
        float inv[4];
        #pragma unroll
        for (int r = 0; r < 4; ++r) inv[r] = 1.0f / l_run[sub][r];
        #pragma unroll
        for (int dt = 0; dt < 4; ++dt)
            #pragma unroll
            for (int r = 0; r < 4; ++r) {
                int row = wv * 32 + sub * 16 + quad * 4 + r;
                Ob[(size_t)row * 64 + dt * 16 + l16] = oacc[sub][dt][r] * inv[r];
            }
    }
}

// ---------------------------------------------------------------------------
extern "C" void kernel_launch(void* const* d_in, const int* in_sizes, int n_in,
                              void* d_out, int out_size, void* d_ws, size_t ws_size,
                              hipStream_t stream)
{
    const float* x  = (const float*)d_in[0];
    const float* Wq = (const float*)d_in[1];
    const float* bq = (const float*)d_in[2];
    const float* Wk = (const float*)d_in[3];
    const float* bk = (const float*)d_in[4];
    const float* Wv = (const float*)d_in[5];
    const float* bv = (const float*)d_in[6];
    const float* Wo = (const float*)d_in[7];
    const float* bo = (const float*)d_in[8];
    float* out = (float*)d_out;

    const int M = BATCH * SEQ;     // 4096
    const int N = D_MODEL;         // 1024
    const int K = D_MODEL;         // 1024
    const size_t NE = (size_t)M * N;   // 4 M elements

    float* ws  = (float*)d_ws;
    float* Q   = ws;
    float* Km  = ws + NE;
    float* Vm  = ws + 2 * NE;
    float* ctx = ws + 3 * NE;
    u16* bws = (u16*)(ws + 4 * NE);
    u16* Qhi = bws;
    u16* Qlo = bws + NE;
    u16* Khi = bws + 2 * NE;
    u16* Klo = bws + 3 * NE;
    u16* Vtb = bws + 4 * NE;

    dim3 blk(256);

    // QKV projections (fp32)
    sgemm_bias3<<<dim3(N / BN, M / BM, 3), blk, 0, stream>>>(
        x, Wq, Wk, Wv, bq, bk, bv, Q, Km, Vm, M, N, K);

    // Split-bf16 conversion + V transpose
    const int n4 = (int)(NE / 4);
    hilo_conv<<<dim3((n4 + 255) / 256), blk, 0, stream>>>(Q,  Qhi, Qlo, n4);
    hilo_conv<<<dim3((n4 + 255) / 256), blk, 0, stream>>>(Km, Khi, Klo, n4);
    v_transpose<<<dim3(SEQ / 64, BH), blk, 0, stream>>>(Vm, Vtb);

    // MFMA flash attention
    attn_mfma<<<dim3(SEQ / 128, BH), blk, 0, stream>>>(Qhi, Qlo, Khi, Klo, Vtb, ctx);

    // Output projection (fp32)
    sgemm_bias3<<<dim3(N / BN, M / BM, 1), blk, 0, stream>>>(
        ctx, Wo, Wo, Wo, bo, bo, bo, out, out, out, M, N, K);
}

// Round 3
// 372.820 us; speedup vs baseline: 2.9715x; 1.7677x over previous
//
#include <hip/hip_runtime.h>
#include <hip/hip_bf16.h>
#include <math.h>

#define D_MODEL 1024
#define SEQ     2048
#define BATCH   2
#define NHEAD   16
#define DKH     64
#define BH      (BATCH * NHEAD)   // 32

typedef unsigned short u16;
typedef unsigned int   u32;
typedef __bf16 bf16x8 __attribute__((ext_vector_type(8)));
typedef float  f32x4  __attribute__((ext_vector_type(4)));

#define MFMA16(a, b, c) __builtin_amdgcn_mfma_f32_16x16x32_bf16((a), (b), (c), 0, 0, 0)
#define AS1 __attribute__((address_space(1)))
#define AS3 __attribute__((address_space(3)))

__device__ __forceinline__ u16 f2bf(float x) {
    u32 u = __float_as_uint(x);
    u += 0x7fffu + ((u >> 16) & 1u);   // RNE (finite data)
    return (u16)(u >> 16);
}
__device__ __forceinline__ float bf2f(u16 b) {
    return __uint_as_float(((u32)b) << 16);
}
// async global->LDS, 16B/lane; lds dest wave-uniform (lane*16 implicit)
__device__ __forceinline__ void gl16(const u16* g, void* lds) {
    __builtin_amdgcn_global_load_lds((const AS1 u32*)g, (AS3 u32*)lds, 16, 0, 0);
}

// ---------------------------------------------------------------------------
// x fp32 -> hi/lo bf16
// ---------------------------------------------------------------------------
__global__ __launch_bounds__(256) void hilo_conv(
    const float* __restrict__ src, u16* __restrict__ hi, u16* __restrict__ lo, int n4)
{
    int i = blockIdx.x * 256 + threadIdx.x;
    if (i >= n4) return;
    float4 v = reinterpret_cast<const float4*>(src)[i];
    float a[4] = {v.x, v.y, v.z, v.w};
    u16 hh[4], ll[4];
    #pragma unroll
    for (int j = 0; j < 4; ++j) {
        u16 hb = f2bf(a[j]);
        hh[j] = hb;
        ll[j] = f2bf(a[j] - bf2f(hb));
    }
    uint2 H, L;
    H.x = hh[0] | ((u32)hh[1] << 16); H.y = hh[2] | ((u32)hh[3] << 16);
    L.x = ll[0] | ((u32)ll[1] << 16); L.y = ll[2] | ((u32)ll[3] << 16);
    reinterpret_cast<uint2*>(hi)[i] = H;
    reinterpret_cast<uint2*>(lo)[i] = L;
}

// ---------------------------------------------------------------------------
// W [K][N] fp32 -> WT hi/lo bf16 [N][K] (transpose + split). z selects matrix.
// ---------------------------------------------------------------------------
__global__ __launch_bounds__(256) void wt_conv(
    const float* __restrict__ W0, const float* __restrict__ W1,
    const float* __restrict__ W2, const float* __restrict__ W3,
    u16* __restrict__ H0, u16* __restrict__ L0, u16* __restrict__ H1, u16* __restrict__ L1,
    u16* __restrict__ H2, u16* __restrict__ L2, u16* __restrict__ H3, u16* __restrict__ L3)
{
    const float* W; u16 *Ht, *Lt;
    if (blockIdx.z == 0)      { W = W0; Ht = H0; Lt = L0; }
    else if (blockIdx.z == 1) { W = W1; Ht = H1; Lt = L1; }
    else if (blockIdx.z == 2) { W = W2; Ht = H2; Lt = L2; }
    else                      { W = W3; Ht = H3; Lt = L3; }

    __shared__ float T[64][65];
    const int n0 = blockIdx.x * 64, k0 = blockIdx.y * 64;
    const int t = threadIdx.x;
    #pragma unroll
    for (int i = 0; i < 4; ++i) {
        int f = t + i * 256;             // 0..1023 float4s
        int kr = f >> 4, ns = (f & 15) * 4;
        float4 v = *reinterpret_cast<const float4*>(&W[(size_t)(k0 + kr) * D_MODEL + n0 + ns]);
        T[kr][ns + 0] = v.x; T[kr][ns + 1] = v.y; T[kr][ns + 2] = v.z; T[kr][ns + 3] = v.w;
    }
    __syncthreads();
    #pragma unroll
    for (int i = 0; i < 4; ++i) {
        int f = t + i * 256;
        int nr = f >> 4, ks = (f & 15) * 4;
        u16 hh[4], ll[4];
        #pragma unroll
        for (int j = 0; j < 4; ++j) {
            float x = T[ks + j][nr];
            u16 hb = f2bf(x);
            hh[j] = hb;
            ll[j] = f2bf(x - bf2f(hb));
        }
        uint2 H, L;
        H.x = hh[0] | ((u32)hh[1] << 16); H.y = hh[2] | ((u32)hh[3] << 16);
        L.x = ll[0] | ((u32)ll[1] << 16); L.y = ll[2] | ((u32)ll[3] << 16);
        size_t o = (size_t)(n0 + nr) * D_MODEL + k0 + ks;
        *reinterpret_cast<uint2*>(&Ht[o]) = H;
        *reinterpret_cast<uint2*>(&Lt[o]) = L;
    }
}

// ---------------------------------------------------------------------------
// Split-bf16 MFMA GEMM: C = A @ WT^T + bias
// 128x128 tile, BK=32, 4 waves (2x2 of 64x64), 3-term split (hh + hl + lh).
// LDS 4 x 8 KB via global_load_lds w16; XOR seg-swizzle seg^((row>>1)&3).
// mode 0: fp32 out; mode 1: hi/lo bf16 out.
// ---------------------------------------------------------------------------
struct GArg {
    const u16* Bh; const u16* Bl; const float* bias;
    float* Cf; u16* Ch; u16* Cl; int mode;
};

__global__ __launch_bounds__(256) void gemm_split(
    const u16* __restrict__ AhG, const u16* __restrict__ AlG,
    GArg g0, GArg g1, GArg g2, int M, int N, int K)
{
    GArg ga = (blockIdx.z == 0) ? g0 : (blockIdx.z == 1) ? g1 : g2;

    __shared__ u16 AhS[128 * 32];
    __shared__ u16 AlS[128 * 32];
    __shared__ u16 BhS[128 * 32];
    __shared__ u16 BlS[128 * 32];

    const int tid  = threadIdx.x;
    const int wv   = tid >> 6;
    const int lane = tid & 63;
    const int quad = lane >> 4;
    const int l16  = lane & 15;
    const int wm   = wv >> 1, wn = wv & 1;
    const int brow = blockIdx.y * 128, bcol = blockIdx.x * 128;

    // loader: each wave DMAs 2 chunks of 1 KB per array (chunk = 16 rows x 64 B)
    size_t aofs[2], bofs[2];
    int ldsb[2];
    #pragma unroll
    for (int j = 0; j < 2; ++j) {
        int c = wv * 2 + j;
        int r = c * 16 + (lane >> 2);
        int gseg = (lane & 3) ^ ((r >> 1) & 3);
        aofs[j] = (size_t)(brow + r) * K + gseg * 8;
        bofs[j] = (size_t)(bcol + r) * K + gseg * 8;
        ldsb[j] = c * 1024;
    }

    // fragment LDS byte offsets (swizzled)
    int aro[4], bro[4];
    #pragma unroll
    for (int i = 0; i < 4; ++i) {
        int mr = wm * 64 + i * 16 + l16;
        aro[i] = mr * 64 + ((quad ^ ((mr >> 1) & 3)) * 16);
        int nr = wn * 64 + i * 16 + l16;
        bro[i] = nr * 64 + ((quad ^ ((nr >> 1) & 3)) * 16);
    }

    f32x4 acc[4][4] = {};

    for (int k0 = 0; k0 < K; k0 += 32) {
        __syncthreads();
        #pragma unroll
        for (int j = 0; j < 2; ++j) {
            gl16(AhG + aofs[j] + k0, (char*)AhS + ldsb[j]);
            gl16(AlG + aofs[j] + k0, (char*)AlS + ldsb[j]);
            gl16(ga.Bh + bofs[j] + k0, (char*)BhS + ldsb[j]);
            gl16(ga.Bl + bofs[j] + k0, (char*)BlS + ldsb[j]);
        }
        __syncthreads();

        bf16x8 ah[4], al[4], bh[4], bl[4];
        #pragma unroll
        for (int i = 0; i < 4; ++i) {
            ah[i] = *reinterpret_cast<const bf16x8*>((const char*)AhS + aro[i]);
            al[i] = *reinterpret_cast<const bf16x8*>((const char*)AlS + aro[i]);
            bh[i] = *reinterpret_cast<const bf16x8*>((const char*)BhS + bro[i]);
            bl[i] = *reinterpret_cast<const bf16x8*>((const char*)BlS + bro[i]);
        }
        #pragma unroll
        for (int mi = 0; mi < 4; ++mi)
            #pragma unroll
            for (int ni = 0; ni < 4; ++ni) {
                f32x4 c = acc[mi][ni];
                c = MFMA16(ah[mi], bh[ni], c);
                c = MFMA16(ah[mi], bl[ni], c);
                c = MFMA16(al[mi], bh[ni], c);
                acc[mi][ni] = c;
            }
    }

    // epilogue
    #pragma unroll
    for (int mi = 0; mi < 4; ++mi) {
        #pragma unroll
        for (int ni = 0; ni < 4; ++ni) {
            int col = bcol + wn * 64 + ni * 16 + l16;
            float bv = ga.bias[col];
            #pragma unroll
            for (int r = 0; r < 4; ++r) {
                int row = brow + wm * 64 + mi * 16 + quad * 4 + r;
                size_t idx = (size_t)row * N + col;
                float v = acc[mi][ni][r] + bv;
                if (ga.mode == 0) {
                    ga.Cf[idx] = v;
                } else {
                    u16 h = f2bf(v);
                    ga.Ch[idx] = h;
                    ga.Cl[idx] = f2bf(v - bf2f(h));
                }
            }
        }
    }
}

// ---------------------------------------------------------------------------
// V fp32 [BH][SEQ][64] -> Vt bf16 [BH][64][SEQ]
// ---------------------------------------------------------------------------
__global__ __launch_bounds__(256) void v_transpose(
    const float* __restrict__ V, u16* __restrict__ Vt)
{
    __shared__ u16 T[64][72];
    const int bh = blockIdx.y, st = blockIdx.x;
    const float* src = V + ((size_t)bh * SEQ + (size_t)st * 64) * 64;
    const int t = threadIdx.x;
    #pragma unroll
    for (int i = 0; i < 4; ++i) {
        int c  = t + i * 256;
        int s  = c >> 4;
        int d0 = (c & 15) * 4;
        float4 v = reinterpret_cast<const float4*>(src)[c];
        T[d0 + 0][s] = f2bf(v.x);
        T[d0 + 1][s] = f2bf(v.y);
        T[d0 + 2][s] = f2bf(v.z);
        T[d0 + 3][s] = f2bf(v.w);
    }
    __syncthreads();
    const int d = t >> 2, seg = t & 3;
    u16* dst = Vt + (size_t)bh * 64 * SEQ + (size_t)d * SEQ + st * 64 + seg * 16;
    uint4 a = *reinterpret_cast<const uint4*>(&T[d][seg * 16]);
    uint4 b = *reinterpret_cast<const uint4*>(&T[d][seg * 16 + 8]);
    reinterpret_cast<uint4*>(dst)[0] = a;
    reinterpret_cast<uint4*>(dst)[1] = b;
}

// ---------------------------------------------------------------------------
// MFMA flash attention (unchanged core); epilogue now emits ctx hi/lo bf16.
// ---------------------------------------------------------------------------
__global__ __launch_bounds__(256, 2) void attn_mfma(
    const u16* __restrict__ Qh_g, const u16* __restrict__ Ql_g,
    const u16* __restrict__ Kh_g, const u16* __restrict__ Kl_g,
    const u16* __restrict__ Vt_g, u16* __restrict__ Ch_g, u16* __restrict__ Cl_g)
{
    __shared__ u16 Kh[64 * 72];
    __shared__ u16 Kl[64 * 72];
    __shared__ u16 Vt[64 * 72];
    __shared__ u16 Pb[128 * 72];
    __shared__ u16 Qh[128 * 64];
    __shared__ u16 Ql[128 * 64];

    const int tid  = threadIdx.x;
    const int wv   = tid >> 6;
    const int lane = tid & 63;
    const int quad = lane >> 4;
    const int l16  = lane & 15;
    const int bh   = blockIdx.y;
    const int qt   = blockIdx.x;

    const size_t qbase = ((size_t)bh * SEQ + (size_t)qt * 128) * 64;
    {
        const uint4* sH = reinterpret_cast<const uint4*>(Qh_g + qbase);
        const uint4* sL = reinterpret_cast<const uint4*>(Ql_g + qbase);
        uint4* dH = reinterpret_cast<uint4*>(Qh);
        uint4* dL = reinterpret_cast<uint4*>(Ql);
        #pragma unroll
        for (int i = 0; i < 4; ++i) {
            dH[tid + i * 256] = sH[tid + i * 256];
            dL[tid + i * 256] = sL[tid + i * 256];
        }
    }
    __syncthreads();

    bf16x8 qf[2][2][2];
    #pragma unroll
    for (int sub = 0; sub < 2; ++sub)
        #pragma unroll
        for (int ks = 0; ks < 2; ++ks) {
            int off = (wv * 32 + sub * 16 + l16) * 64 + ks * 32 + quad * 8;
            qf[sub][ks][0] = *reinterpret_cast<const bf16x8*>(&Qh[off]);
            qf[sub][ks][1] = *reinterpret_cast<const bf16x8*>(&Ql[off]);
        }

    f32x4 oacc[2][4] = {};
    float m_run[2][4], l_run[2][4];
    #pragma unroll
    for (int s = 0; s < 2; ++s)
        #pragma unroll
        for (int r = 0; r < 4; ++r) { m_run[s][r] = -1e30f; l_run[s][r] = 0.f; }

    const size_t kbh  = (size_t)bh * SEQ * 64;
    const size_t vtbh = (size_t)bh * 64 * SEQ;

    for (int kt = 0; kt < SEQ / 64; ++kt) {
        __syncthreads();
        {
            const size_t kof = kbh + (size_t)kt * 64 * 64;
            #pragma unroll
            for (int i = 0; i < 2; ++i) {
                int c = tid + i * 256;
                int row = c >> 3, seg = c & 7;
                *reinterpret_cast<uint4*>(&Kh[row * 72 + seg * 8]) =
                    *reinterpret_cast<const uint4*>(&Kh_g[kof + (size_t)c * 8]);
                *reinterpret_cast<uint4*>(&Kl[row * 72 + seg * 8]) =
                    *reinterpret_cast<const uint4*>(&Kl_g[kof + (size_t)c * 8]);
                *reinterpret_cast<uint4*>(&Vt[row * 72 + seg * 8]) =
                    *reinterpret_cast<const uint4*>(&Vt_g[vtbh + (size_t)row * SEQ + kt * 64 + seg * 8]);
            }
        }
        __syncthreads();

        f32x4 sacc[2][4] = {};
        #pragma unroll
        for (int t4 = 0; t4 < 4; ++t4) {
            bf16x8 kh[2], kl[2];
            #pragma unroll
            for (int ks = 0; ks < 2; ++ks) {
                int off = (t4 * 16 + l16) * 72 + ks * 32 + quad * 8;
                kh[ks] = *reinterpret_cast<const bf16x8*>(&Kh[off]);
                kl[ks] = *reinterpret_cast<const bf16x8*>(&Kl[off]);
            }
            #pragma unroll
            for (int sub = 0; sub < 2; ++sub) {
                f32x4 a = sacc[sub][t4];
                #pragma unroll
                for (int ks = 0; ks < 2; ++ks) {
                    a = MFMA16(qf[sub][ks][0], kh[ks], a);
                    a = MFMA16(qf[sub][ks][0], kl[ks], a);
                    a = MFMA16(qf[sub][ks][1], kh[ks], a);
                }
                sacc[sub][t4] = a;
            }
        }

        #pragma unroll
        for (int sub = 0; sub < 2; ++sub) {
            #pragma unroll
            for (int t4 = 0; t4 < 4; ++t4) sacc[sub][t4] *= 0.125f;
            #pragma unroll
            for (int r = 0; r < 4; ++r) {
                float s0 = sacc[sub][0][r], s1 = sacc[sub][1][r];
                float s2 = sacc[sub][2][r], s3 = sacc[sub][3][r];
                float mx = fmaxf(fmaxf(s0, s1), fmaxf(s2, s3));
                #pragma unroll
                for (int m = 1; m < 16; m <<= 1) mx = fmaxf(mx, __shfl_xor(mx, m, 64));
                float mnew  = fmaxf(m_run[sub][r], mx);
                float alpha = __expf(m_run[sub][r] - mnew);
                m_run[sub][r] = mnew;
                float p0 = __expf(s0 - mnew), p1 = __expf(s1 - mnew);
                float p2 = __expf(s2 - mnew), p3 = __expf(s3 - mnew);
                float rs = (p0 + p1) + (p2 + p3);
                #pragma unroll
                for (int m = 1; m < 16; m <<= 1) rs += __shfl_xor(rs, m, 64);
                l_run[sub][r] = l_run[sub][r] * alpha + rs;
                int row = wv * 32 + sub * 16 + quad * 4 + r;
                Pb[row * 72 +  0 + l16] = f2bf(p0);
                Pb[row * 72 + 16 + l16] = f2bf(p1);
                Pb[row * 72 + 32 + l16] = f2bf(p2);
                Pb[row * 72 + 48 + l16] = f2bf(p3);
                #pragma unroll
                for (int dt = 0; dt < 4; ++dt) oacc[sub][dt][r] *= alpha;
            }
        }

        #pragma unroll
        for (int sub = 0; sub < 2; ++sub) {
            bf16x8 ap[2];
            #pragma unroll
            for (int ks = 0; ks < 2; ++ks)
                ap[ks] = *reinterpret_cast<const bf16x8*>(
                    &Pb[(wv * 32 + sub * 16 + l16) * 72 + ks * 32 + quad * 8]);
            #pragma unroll
            for (int dt = 0; dt < 4; ++dt) {
                #pragma unroll
                for (int ks = 0; ks < 2; ++ks) {
                    bf16x8 bv = *reinterpret_cast<const bf16x8*>(
                        &Vt[(dt * 16 + l16) * 72 + ks * 32 + quad * 8]);
                    oacc[sub][dt] = MFMA16(ap[ks], bv, oacc[sub][dt]);
                }
            }
        }
    }

    // epilogue: normalize, split to hi/lo bf16 ctx
    u16* Oh = Ch_g + qbase;
    u16* Ol = Cl_g + qbase;
    #pragma unroll
    for (int sub = 0; sub < 2; ++sub) {
        float inv[4];
        #pragma unroll
        for (int r = 0; r < 4; ++r) inv[r] = 1.0f / l_run[sub][r];
        #pragma unroll
        for (int dt = 0; dt < 4; ++dt)
            #pragma unroll
            for (int r = 0; r < 4; ++r) {
                int row = wv * 32 + sub * 16 + quad * 4 + r;
                float v = oacc[sub][dt][r] * inv[r];
                u16 h = f2bf(v);
                size_t idx = (size_t)row * 64 + dt * 16 + l16;
                Oh[idx] = h;
                Ol[idx] = f2bf(v - bf2f(h));
            }
    }
}

// ---------------------------------------------------------------------------
extern "C" void kernel_launch(void* const* d_in, const int* in_sizes, int n_in,
                              void* d_out, int out_size, void* d_ws, size_t ws_size,
                              hipStream_t stream)
{
    const float* x  = (const float*)d_in[0];
    const float* Wq = (const float*)d_in[1];
    const float* bq = (const float*)d_in[2];
    const float* Wk = (const float*)d_in[3];
    const float* bk = (const float*)d_in[4];
    const float* Wv = (const float*)d_in[5];
    const float* bv = (const float*)d_in[6];
    const float* Wo = (const float*)d_in[7];
    const float* bo = (const float*)d_in[8];
    float* out = (float*)d_out;

    const int M = BATCH * SEQ;        // 4096
    const int N = D_MODEL;            // 1024
    const int K = D_MODEL;            // 1024
    const size_t NE = (size_t)M * N;  // 4,194,304
    const size_t NW = (size_t)N * K;  // 1,048,576

    u16* w16 = (u16*)d_ws;
    u16* Xh   = w16;
    u16* Xl   = Xh   + NE;
    u16* Qh   = Xl   + NE;
    u16* Ql   = Qh   + NE;
    u16* Kh   = Ql   + NE;
    u16* Kl   = Kh   + NE;
    u16* Ctxh = Kl   + NE;
    u16* Ctxl = Ctxh + NE;
    u16* Vtb  = Ctxl + NE;
    u16* WTqh = Vtb  + NE;
    u16* WTql = WTqh + NW;
    u16* WTkh = WTql + NW;
    u16* WTkl = WTkh + NW;
    u16* WTvh = WTkl + NW;
    u16* WTvl = WTvh + NW;
    u16* WToh = WTvl + NW;
    u16* WTol = WToh + NW;
    float* Vf = (float*)(WTol + NW);

    dim3 blk(256);

    // input conversions
    hilo_conv<<<dim3((int)(NE / 4 / 256)), blk, 0, stream>>>(x, Xh, Xl, (int)(NE / 4));
    wt_conv<<<dim3(16, 16, 4), blk, 0, stream>>>(
        Wq, Wk, Wv, Wo, WTqh, WTql, WTkh, WTkl, WTvh, WTvl, WToh, WTol);

    // QKV projections (split-bf16 MFMA); Q,K -> hi/lo, V -> fp32
    GArg aq = {WTqh, WTql, bq, nullptr, Qh, Ql, 1};
    GArg ak = {WTkh, WTkl, bk, nullptr, Kh, Kl, 1};
    GArg av = {WTvh, WTvl, bv, Vf, nullptr, nullptr, 0};
    gemm_split<<<dim3(N / 128, M / 128, 3), blk, 0, stream>>>(Xh, Xl, aq, ak, av, M, N, K);

    v_transpose<<<dim3(SEQ / 64, BH), blk, 0, stream>>>(Vf, Vtb);

    // attention -> ctx hi/lo
    attn_mfma<<<dim3(SEQ / 128, BH), blk, 0, stream>>>(Qh, Ql, Kh, Kl, Vtb, Ctxh, Ctxl);

    // output projection
    GArg ao = {WToh, WTol, bo, out, nullptr, nullptr, 0};
    gemm_split<<<dim3(N / 128, M / 128, 1), blk, 0, stream>>>(Ctxh, Ctxl, ao, ao, ao, M, N, K);
}

// Round 5
// 324.753 us; speedup vs baseline: 3.4113x; 1.1480x over previous
//
#include <hip/hip_runtime.h>
#include <hip/hip_bf16.h>
#include <math.h>

#define D_MODEL 1024
#define SEQ     2048
#define BATCH   2
#define NHEAD   16
#define DKH     64
#define BH      (BATCH * NHEAD)   // 32

typedef unsigned short u16;
typedef unsigned int   u32;
typedef __bf16 bf16x8 __attribute__((ext_vector_type(8)));
typedef float  f32x4  __attribute__((ext_vector_type(4)));

#define MFMA16(a, b, c) __builtin_amdgcn_mfma_f32_16x16x32_bf16((a), (b), (c), 0, 0, 0)
#define AS1 __attribute__((address_space(1)))
#define AS3 __attribute__((address_space(3)))

__device__ __forceinline__ u16 f2bf(float x) {
    u32 u = __float_as_uint(x);
    u += 0x7fffu + ((u >> 16) & 1u);   // RNE (finite data)
    return (u16)(u >> 16);
}
__device__ __forceinline__ float bf2f(u16 b) {
    return __uint_as_float(((u32)b) << 16);
}
// async global->LDS, 16B/lane; lds dest wave-uniform (lane*16 implicit)
__device__ __forceinline__ void gl16(const u16* g, void* lds) {
    __builtin_amdgcn_global_load_lds((const AS1 u32*)g, (AS3 u32*)lds, 16, 0, 0);
}

// ---------------------------------------------------------------------------
// x fp32 -> hi/lo bf16
// ---------------------------------------------------------------------------
__global__ __launch_bounds__(256) void hilo_conv(
    const float* __restrict__ src, u16* __restrict__ hi, u16* __restrict__ lo, int n4)
{
    int i = blockIdx.x * 256 + threadIdx.x;
    if (i >= n4) return;
    float4 v = reinterpret_cast<const float4*>(src)[i];
    float a[4] = {v.x, v.y, v.z, v.w};
    u16 hh[4], ll[4];
    #pragma unroll
    for (int j = 0; j < 4; ++j) {
        u16 hb = f2bf(a[j]);
        hh[j] = hb;
        ll[j] = f2bf(a[j] - bf2f(hb));
    }
    uint2 H, L;
    H.x = hh[0] | ((u32)hh[1] << 16); H.y = hh[2] | ((u32)hh[3] << 16);
    L.x = ll[0] | ((u32)ll[1] << 16); L.y = ll[2] | ((u32)ll[3] << 16);
    reinterpret_cast<uint2*>(hi)[i] = H;
    reinterpret_cast<uint2*>(lo)[i] = L;
}

// ---------------------------------------------------------------------------
// W [K][N] fp32 -> WT hi/lo bf16 [N][K] (transpose + split). z selects matrix.
// ---------------------------------------------------------------------------
__global__ __launch_bounds__(256) void wt_conv(
    const float* __restrict__ W0, const float* __restrict__ W1,
    const float* __restrict__ W2, const float* __restrict__ W3,
    u16* __restrict__ H0, u16* __restrict__ L0, u16* __restrict__ H1, u16* __restrict__ L1,
    u16* __restrict__ H2, u16* __restrict__ L2, u16* __restrict__ H3, u16* __restrict__ L3)
{
    const float* W; u16 *Ht, *Lt;
    if (blockIdx.z == 0)      { W = W0; Ht = H0; Lt = L0; }
    else if (blockIdx.z == 1) { W = W1; Ht = H1; Lt = L1; }
    else if (blockIdx.z == 2) { W = W2; Ht = H2; Lt = L2; }
    else                      { W = W3; Ht = H3; Lt = L3; }

    __shared__ float T[64][65];
    const int n0 = blockIdx.x * 64, k0 = blockIdx.y * 64;
    const int t = threadIdx.x;
    #pragma unroll
    for (int i = 0; i < 4; ++i) {
        int f = t + i * 256;             // 0..1023 float4s
        int kr = f >> 4, ns = (f & 15) * 4;
        float4 v = *reinterpret_cast<const float4*>(&W[(size_t)(k0 + kr) * D_MODEL + n0 + ns]);
        T[kr][ns + 0] = v.x; T[kr][ns + 1] = v.y; T[kr][ns + 2] = v.z; T[kr][ns + 3] = v.w;
    }
    __syncthreads();
    #pragma unroll
    for (int i = 0; i < 4; ++i) {
        int f = t + i * 256;
        int nr = f >> 4, ks = (f & 15) * 4;
        u16 hh[4], ll[4];
        #pragma unroll
        for (int j = 0; j < 4; ++j) {
            float x = T[ks + j][nr];
            u16 hb = f2bf(x);
            hh[j] = hb;
            ll[j] = f2bf(x - bf2f(hb));
        }
        uint2 H, L;
        H.x = hh[0] | ((u32)hh[1] << 16); H.y = hh[2] | ((u32)hh[3] << 16);
        L.x = ll[0] | ((u32)ll[1] << 16); L.y = ll[2] | ((u32)ll[3] << 16);
        size_t o = (size_t)(n0 + nr) * D_MODEL + k0 + ks;
        *reinterpret_cast<uint2*>(&Ht[o]) = H;
        *reinterpret_cast<uint2*>(&Lt[o]) = L;
    }
}

// ---------------------------------------------------------------------------
// Split-bf16 MFMA GEMM: C = A @ WT^T + bias
// 128x128 tile, BK=32, 4 waves (2x2 of 64x64), 3-term split (hh + hl + lh).
// mode 0: fp32 out; mode 1: hi/lo bf16 out; mode 3: flat bf16 out (Ch only).
// ---------------------------------------------------------------------------
struct GArg {
    const u16* Bh; const u16* Bl; const float* bias;
    float* Cf; u16* Ch; u16* Cl; int mode;
};

__global__ __launch_bounds__(256) void gemm_split(
    const u16* __restrict__ AhG, const u16* __restrict__ AlG,
    GArg g0, GArg g1, GArg g2, int M, int N, int K)
{
    GArg ga = (blockIdx.z == 0) ? g0 : (blockIdx.z == 1) ? g1 : g2;

    __shared__ u16 AhS[128 * 32];
    __shared__ u16 AlS[128 * 32];
    __shared__ u16 BhS[128 * 32];
    __shared__ u16 BlS[128 * 32];

    const int tid  = threadIdx.x;
    const int wv   = tid >> 6;
    const int lane = tid & 63;
    const int quad = lane >> 4;
    const int l16  = lane & 15;
    const int wm   = wv >> 1, wn = wv & 1;
    const int brow = blockIdx.y * 128, bcol = blockIdx.x * 128;

    size_t aofs[2], bofs[2];
    int ldsb[2];
    #pragma unroll
    for (int j = 0; j < 2; ++j) {
        int c = wv * 2 + j;
        int r = c * 16 + (lane >> 2);
        int gseg = (lane & 3) ^ ((r >> 1) & 3);
        aofs[j] = (size_t)(brow + r) * K + gseg * 8;
        bofs[j] = (size_t)(bcol + r) * K + gseg * 8;
        ldsb[j] = c * 1024;
    }

    int aro[4], bro[4];
    #pragma unroll
    for (int i = 0; i < 4; ++i) {
        int mr = wm * 64 + i * 16 + l16;
        aro[i] = mr * 64 + ((quad ^ ((mr >> 1) & 3)) * 16);
        int nr = wn * 64 + i * 16 + l16;
        bro[i] = nr * 64 + ((quad ^ ((nr >> 1) & 3)) * 16);
    }

    f32x4 acc[4][4] = {};

    for (int k0 = 0; k0 < K; k0 += 32) {
        __syncthreads();
        #pragma unroll
        for (int j = 0; j < 2; ++j) {
            gl16(AhG + aofs[j] + k0, (char*)AhS + ldsb[j]);
            gl16(AlG + aofs[j] + k0, (char*)AlS + ldsb[j]);
            gl16(ga.Bh + bofs[j] + k0, (char*)BhS + ldsb[j]);
            gl16(ga.Bl + bofs[j] + k0, (char*)BlS + ldsb[j]);
        }
        __syncthreads();

        bf16x8 ah[4], al[4], bh[4], bl[4];
        #pragma unroll
        for (int i = 0; i < 4; ++i) {
            ah[i] = *reinterpret_cast<const bf16x8*>((const char*)AhS + aro[i]);
            al[i] = *reinterpret_cast<const bf16x8*>((const char*)AlS + aro[i]);
            bh[i] = *reinterpret_cast<const bf16x8*>((const char*)BhS + bro[i]);
            bl[i] = *reinterpret_cast<const bf16x8*>((const char*)BlS + bro[i]);
        }
        #pragma unroll
        for (int mi = 0; mi < 4; ++mi)
            #pragma unroll
            for (int ni = 0; ni < 4; ++ni) {
                f32x4 c = acc[mi][ni];
                c = MFMA16(ah[mi], bh[ni], c);
                c = MFMA16(ah[mi], bl[ni], c);
                c = MFMA16(al[mi], bh[ni], c);
                acc[mi][ni] = c;
            }
    }

    // epilogue
    #pragma unroll
    for (int mi = 0; mi < 4; ++mi) {
        #pragma unroll
        for (int ni = 0; ni < 4; ++ni) {
            int col = bcol + wn * 64 + ni * 16 + l16;
            float bv = ga.bias[col];
            #pragma unroll
            for (int r = 0; r < 4; ++r) {
                int row = brow + wm * 64 + mi * 16 + quad * 4 + r;
                size_t idx = (size_t)row * N + col;
                float v = acc[mi][ni][r] + bv;
                if (ga.mode == 0) {
                    ga.Cf[idx] = v;
                } else if (ga.mode == 1) {
                    u16 h = f2bf(v);
                    ga.Ch[idx] = h;
                    ga.Cl[idx] = f2bf(v - bf2f(h));
                } else {
                    ga.Ch[idx] = f2bf(v);
                }
            }
        }
    }
}

// ---------------------------------------------------------------------------
// V bf16 flat [BH][SEQ][64] (contiguous reshape slabs) -> Vt bf16 [BH][64][SEQ]
// ---------------------------------------------------------------------------
__global__ __launch_bounds__(256) void v_transpose(
    const u16* __restrict__ V, u16* __restrict__ Vt)
{
    __shared__ u16 T[64][72];
    const int bh = blockIdx.y, st = blockIdx.x;
    const u16* src = V + ((size_t)bh * SEQ + (size_t)st * 64) * 64;
    const int t = threadIdx.x;
    #pragma unroll
    for (int i = 0; i < 2; ++i) {
        int c  = t + i * 256;            // 0..511 uint4 chunks (8 u16 each)
        int s  = c >> 3;                 // 0..63
        int d0 = (c & 7) * 8;
        uint4 v = reinterpret_cast<const uint4*>(src)[c];
        u16 e[8];
        e[0] = (u16)(v.x & 0xffff); e[1] = (u16)(v.x >> 16);
        e[2] = (u16)(v.y & 0xffff); e[3] = (u16)(v.y >> 16);
        e[4] = (u16)(v.z & 0xffff); e[5] = (u16)(v.z >> 16);
        e[6] = (u16)(v.w & 0xffff); e[7] = (u16)(v.w >> 16);
        #pragma unroll
        for (int j = 0; j < 8; ++j) T[d0 + j][s] = e[j];
    }
    __syncthreads();
    const int d = t >> 2, seg = t & 3;
    u16* dst = Vt + (size_t)bh * 64 * SEQ + (size_t)d * SEQ + st * 64 + seg * 16;
    uint4 a = *reinterpret_cast<const uint4*>(&T[d][seg * 16]);
    uint4 b = *reinterpret_cast<const uint4*>(&T[d][seg * 16 + 8]);
    reinterpret_cast<uint4*>(dst)[0] = a;
    reinterpret_cast<uint4*>(dst)[1] = b;
}

// ---------------------------------------------------------------------------
// MFMA flash attention, no-max softmax (uniform exp shift cancels in l).
// grid = (16 q-tiles of 128, 32 bh), block = 256 (4 waves).
// All tiles DMA'd via global_load_lds w16 with 3-bit XOR seg swizzle.
// ---------------------------------------------------------------------------
__global__ __launch_bounds__(256, 2) void attn_mfma(
    const u16* __restrict__ Qh_g, const u16* __restrict__ Ql_g,
    const u16* __restrict__ Kh_g, const u16* __restrict__ Kl_g,
    const u16* __restrict__ Vt_g, u16* __restrict__ Ch_g, u16* __restrict__ Cl_g)
{
    __shared__ u16 KhS[64 * 64];
    __shared__ u16 KlS[64 * 64];
    __shared__ u16 VtS[64 * 64];
    __shared__ u16 Pb [128 * 72];
    __shared__ u16 QhS[128 * 64];
    __shared__ u16 QlS[128 * 64];

    const int tid  = threadIdx.x;
    const int wv   = tid >> 6;
    const int lane = tid & 63;
    const int quad = lane >> 4;
    const int l16  = lane & 15;
    const int bh   = blockIdx.y;
    const int qt   = blockIdx.x;

    const size_t qbase = ((size_t)bh * SEQ + (size_t)qt * 128) * 64;
    const size_t kbh   = (size_t)bh * SEQ * 64;
    const size_t vtbh  = (size_t)bh * 64 * SEQ;

    // ---- Q DMA: 16 x 1KB chunks per array; wave w -> chunks 4w..4w+3 ----
    #pragma unroll
    for (int j = 0; j < 4; ++j) {
        int c   = wv * 4 + j;
        int row = c * 8 + (lane >> 3);
        int sg  = (lane & 7) ^ (row & 7);
        size_t go = qbase + (size_t)row * 64 + sg * 8;
        gl16(Qh_g + go, (char*)QhS + c * 1024);
        gl16(Ql_g + go, (char*)QlS + c * 1024);
    }

    // K/V staging addresses; chunk c = wv*2 + j (8 rows each)
    size_t kofs[2], vofs[2];
    int ldsb[2];
    #pragma unroll
    for (int j = 0; j < 2; ++j) {
        int c   = wv * 2 + j;
        int row = c * 8 + (lane >> 3);
        int sg  = (lane & 7) ^ (row & 7);
        kofs[j] = kbh  + (size_t)row * 64 + sg * 8;
        vofs[j] = vtbh + (size_t)row * SEQ + sg * 8;
        ldsb[j] = c * 1024;
    }

    // fragment LDS byte offsets: row = t*16 + l16; swizzle = (ks*4+quad)^(l16&7)
    int fro[4][2];
    #pragma unroll
    for (int t = 0; t < 4; ++t)
        #pragma unroll
        for (int ks = 0; ks < 2; ++ks)
            fro[t][ks] = (t * 16 + l16) * 128 + (((ks * 4 + quad) ^ (l16 & 7)) * 16);

    __syncthreads();   // vmcnt(0) drained -> Q resident

    bf16x8 qf[2][2][2];   // [sub][ks][hi/lo]
    #pragma unroll
    for (int sub = 0; sub < 2; ++sub)
        #pragma unroll
        for (int ks = 0; ks < 2; ++ks) {
            int row = wv * 32 + sub * 16 + l16;
            int off = row * 128 + (((ks * 4 + quad) ^ (l16 & 7)) * 16);
            qf[sub][ks][0] = *reinterpret_cast<const bf16x8*>((const char*)QhS + off);
            qf[sub][ks][1] = *reinterpret_cast<const bf16x8*>((const char*)QlS + off);
        }

    f32x4 oacc[2][4] = {};
    float psum[2][4] = {};

    for (int kt = 0; kt < SEQ / 64; ++kt) {
        __syncthreads();
        #pragma unroll
        for (int j = 0; j < 2; ++j) {
            size_t ko = kofs[j] + (size_t)kt * 64 * 64;
            gl16(Kh_g + ko, (char*)KhS + ldsb[j]);
            gl16(Kl_g + ko, (char*)KlS + ldsb[j]);
            gl16(Vt_g + vofs[j] + kt * 64, (char*)VtS + ldsb[j]);
        }
        __syncthreads();

        // ---- S = Q K^T (3-term split) ----
        f32x4 sacc[2][4] = {};
        #pragma unroll
        for (int t4 = 0; t4 < 4; ++t4) {
            bf16x8 kh[2], kl[2];
            #pragma unroll
            for (int ks = 0; ks < 2; ++ks) {
                kh[ks] = *reinterpret_cast<const bf16x8*>((const char*)KhS + fro[t4][ks]);
                kl[ks] = *reinterpret_cast<const bf16x8*>((const char*)KlS + fro[t4][ks]);
            }
            #pragma unroll
            for (int sub = 0; sub < 2; ++sub) {
                f32x4 a = sacc[sub][t4];
                a = MFMA16(qf[sub][0][0], kh[0], a);
                a = MFMA16(qf[sub][0][0], kl[0], a);
                a = MFMA16(qf[sub][0][1], kh[0], a);
                a = MFMA16(qf[sub][1][0], kh[1], a);
                a = MFMA16(qf[sub][1][0], kl[1], a);
                a = MFMA16(qf[sub][1][1], kh[1], a);
                sacc[sub][t4] = a;
            }
        }

        // ---- p = exp(s/8 - 11.09); uniform shift cancels in normalization ----
        #pragma unroll
        for (int sub = 0; sub < 2; ++sub) {
            int rowb = wv * 32 + sub * 16 + quad * 4;
            #pragma unroll
            for (int r = 0; r < 4; ++r) {
                float p0 = __expf(fmaf(sacc[sub][0][r], 0.125f, -11.0903549f));
                float p1 = __expf(fmaf(sacc[sub][1][r], 0.125f, -11.0903549f));
                float p2 = __expf(fmaf(sacc[sub][2][r], 0.125f, -11.0903549f));
                float p3 = __expf(fmaf(sacc[sub][3][r], 0.125f, -11.0903549f));
                psum[sub][r] += (p0 + p1) + (p2 + p3);
                int ro = (rowb + r) * 72 + l16;
                Pb[ro +  0] = f2bf(p0);
                Pb[ro + 16] = f2bf(p1);
                Pb[ro + 32] = f2bf(p2);
                Pb[ro + 48] = f2bf(p3);
            }
        }
        // Pb rows are wave-private: lgkmcnt ordering only, no barrier.

        // ---- O += P @ V ----
        #pragma unroll
        for (int sub = 0; sub < 2; ++sub) {
            bf16x8 ap[2];
            #pragma unroll
            for (int ks = 0; ks < 2; ++ks)
                ap[ks] = *reinterpret_cast<const bf16x8*>(
                    &Pb[(wv * 32 + sub * 16 + l16) * 72 + ks * 32 + quad * 8]);
            #pragma unroll
            for (int dt = 0; dt < 4; ++dt) {
                #pragma unroll
                for (int ks = 0; ks < 2; ++ks) {
                    bf16x8 bv = *reinterpret_cast<const bf16x8*>((const char*)VtS + fro[dt][ks]);
                    oacc[sub][dt] = MFMA16(ap[ks], bv, oacc[sub][dt]);
                }
            }
        }
    }

    // ---- row-sum reduction across the 16 k-lanes (once) ----
    #pragma unroll
    for (int sub = 0; sub < 2; ++sub)
        #pragma unroll
        for (int r = 0; r < 4; ++r) {
            float s = psum[sub][r];
            s += __shfl_xor(s, 1, 64);
            s += __shfl_xor(s, 2, 64);
            s += __shfl_xor(s, 4, 64);
            s += __shfl_xor(s, 8, 64);
            psum[sub][r] = s;
        }

    // ---- epilogue: normalize, split to hi/lo bf16 ctx ----
    u16* Oh = Ch_g + qbase;
    u16* Ol = Cl_g + qbase;
    #pragma unroll
    for (int sub = 0; sub < 2; ++sub) {
        float inv[4];
        #pragma unroll
        for (int r = 0; r < 4; ++r) inv[r] = 1.0f / psum[sub][r];
        #pragma unroll
        for (int dt = 0; dt < 4; ++dt)
            #pragma unroll
            for (int r = 0; r < 4; ++r) {
                int row = wv * 32 + sub * 16 + quad * 4 + r;
                float v = oacc[sub][dt][r] * inv[r];
                u16 h = f2bf(v);
                size_t idx = (size_t)row * 64 + dt * 16 + l16;
                Oh[idx] = h;
                Ol[idx] = f2bf(v - bf2f(h));
            }
    }
}

// ---------------------------------------------------------------------------
extern "C" void kernel_launch(void* const* d_in, const int* in_sizes, int n_in,
                              void* d_out, int out_size, void* d_ws, size_t ws_size,
                              hipStream_t stream)
{
    const float* x  = (const float*)d_in[0];
    const float* Wq = (const float*)d_in[1];
    const float* bq = (const float*)d_in[2];
    const float* Wk = (const float*)d_in[3];
    const float* bk = (const float*)d_in[4];
    const float* Wv = (const float*)d_in[5];
    const float* bv = (const float*)d_in[6];
    const float* Wo = (const float*)d_in[7];
    const float* bo = (const float*)d_in[8];
    float* out = (float*)d_out;

    const int M = BATCH * SEQ;        // 4096
    const int N = D_MODEL;            // 1024
    const int K = D_MODEL;            // 1024
    const size_t NE = (size_t)M * N;  // 4,194,304
    const size_t NW = (size_t)N * K;  // 1,048,576

    u16* w16 = (u16*)d_ws;
    u16* Xh   = w16;
    u16* Xl   = Xh   + NE;
    u16* Qh   = Xl   + NE;
    u16* Ql   = Qh   + NE;
    u16* Kh   = Ql   + NE;
    u16* Kl   = Kh   + NE;
    u16* Ctxh = Kl   + NE;
    u16* Ctxl = Ctxh + NE;
    u16* Vtb  = Ctxl + NE;
    u16* Vb16 = Vtb  + NE;
    u16* WTqh = Vb16 + NE;
    u16* WTql = WTqh + NW;
    u16* WTkh = WTql + NW;
    u16* WTkl = WTkh + NW;
    u16* WTvh = WTkl + NW;
    u16* WTvl = WTvh + NW;
    u16* WToh = WTvl + NW;
    u16* WTol = WToh + NW;

    dim3 blk(256);

    // input conversions
    hilo_conv<<<dim3((int)(NE / 4 / 256)), blk, 0, stream>>>(x, Xh, Xl, (int)(NE / 4));
    wt_conv<<<dim3(16, 16, 4), blk, 0, stream>>>(
        Wq, Wk, Wv, Wo, WTqh, WTql, WTkh, WTkl, WTvh, WTvl, WToh, WTol);

    // QKV projections: Q,K -> hi/lo bf16; V -> flat bf16
    GArg aq = {WTqh, WTql, bq, nullptr, Qh, Ql, 1};
    GArg ak = {WTkh, WTkl, bk, nullptr, Kh, Kl, 1};
    GArg av = {WTvh, WTvl, bv, nullptr, Vb16, nullptr, 3};
    gemm_split<<<dim3(N / 128, M / 128, 3), blk, 0, stream>>>(Xh, Xl, aq, ak, av, M, N, K);

    // transpose V per contiguous reshape slab (bf16 in, bf16 out)
    v_transpose<<<dim3(SEQ / 64, BH), blk, 0, stream>>>(Vb16, Vtb);

    // attention -> ctx hi/lo
    attn_mfma<<<dim3(SEQ / 128, BH), blk, 0, stream>>>(Qh, Ql, Kh, Kl, Vtb, Ctxh, Ctxl);

    // output projection
    GArg ao = {WToh, WTol, bo, out, nullptr, nullptr, 0};
    gemm_split<<<dim3(N / 128, M / 128, 1), blk, 0, stream>>>(Ctxh, Ctxl, ao, ao, ao, M, N, K);
}

// Round 6
// 323.484 us; speedup vs baseline: 3.4247x; 1.0039x over previous
//
#include <hip/hip_runtime.h>
#include <hip/hip_bf16.h>
#include <math.h>

#define D_MODEL 1024
#define SEQ     2048
#define BATCH   2
#define NHEAD   16
#define DKH     64
#define BH      (BATCH * NHEAD)   // 32

typedef unsigned short u16;
typedef unsigned int   u32;
typedef __bf16 bf16x8 __attribute__((ext_vector_type(8)));
typedef float  f32x4  __attribute__((ext_vector_type(4)));

#define MFMA16(a, b, c) __builtin_amdgcn_mfma_f32_16x16x32_bf16((a), (b), (c), 0, 0, 0)
#define AS1 __attribute__((address_space(1)))
#define AS3 __attribute__((address_space(3)))

__device__ __forceinline__ u16 f2bf(float x) {
    u32 u = __float_as_uint(x);
    u += 0x7fffu + ((u >> 16) & 1u);   // RNE (finite data)
    return (u16)(u >> 16);
}
__device__ __forceinline__ float bf2f(u16 b) {
    return __uint_as_float(((u32)b) << 16);
}
// async global->LDS, 16B/lane; lds dest wave-uniform (lane*16 implicit)
__device__ __forceinline__ void gl16(const u16* g, void* lds) {
    __builtin_amdgcn_global_load_lds((const AS1 u32*)g, (AS3 u32*)lds, 16, 0, 0);
}

// ---------------------------------------------------------------------------
// x fp32 -> hi/lo bf16
// ---------------------------------------------------------------------------
__global__ __launch_bounds__(256) void hilo_conv(
    const float* __restrict__ src, u16* __restrict__ hi, u16* __restrict__ lo, int n4)
{
    int i = blockIdx.x * 256 + threadIdx.x;
    if (i >= n4) return;
    float4 v = reinterpret_cast<const float4*>(src)[i];
    float a[4] = {v.x, v.y, v.z, v.w};
    u16 hh[4], ll[4];
    #pragma unroll
    for (int j = 0; j < 4; ++j) {
        u16 hb = f2bf(a[j]);
        hh[j] = hb;
        ll[j] = f2bf(a[j] - bf2f(hb));
    }
    uint2 H, L;
    H.x = hh[0] | ((u32)hh[1] << 16); H.y = hh[2] | ((u32)hh[3] << 16);
    L.x = ll[0] | ((u32)ll[1] << 16); L.y = ll[2] | ((u32)ll[3] << 16);
    reinterpret_cast<uint2*>(hi)[i] = H;
    reinterpret_cast<uint2*>(lo)[i] = L;
}

// ---------------------------------------------------------------------------
// W [K][N] fp32 -> WT hi/lo bf16 [N][K] (transpose + split). z selects matrix.
// ---------------------------------------------------------------------------
__global__ __launch_bounds__(256) void wt_conv(
    const float* __restrict__ W0, const float* __restrict__ W1,
    const float* __restrict__ W2, const float* __restrict__ W3,
    u16* __restrict__ H0, u16* __restrict__ L0, u16* __restrict__ H1, u16* __restrict__ L1,
    u16* __restrict__ H2, u16* __restrict__ L2, u16* __restrict__ H3, u16* __restrict__ L3)
{
    const float* W; u16 *Ht, *Lt;
    if (blockIdx.z == 0)      { W = W0; Ht = H0; Lt = L0; }
    else if (blockIdx.z == 1) { W = W1; Ht = H1; Lt = L1; }
    else if (blockIdx.z == 2) { W = W2; Ht = H2; Lt = L2; }
    else                      { W = W3; Ht = H3; Lt = L3; }

    __shared__ float T[64][65];
    const int n0 = blockIdx.x * 64, k0 = blockIdx.y * 64;
    const int t = threadIdx.x;
    #pragma unroll
    for (int i = 0; i < 4; ++i) {
        int f = t + i * 256;             // 0..1023 float4s
        int kr = f >> 4, ns = (f & 15) * 4;
        float4 v = *reinterpret_cast<const float4*>(&W[(size_t)(k0 + kr) * D_MODEL + n0 + ns]);
        T[kr][ns + 0] = v.x; T[kr][ns + 1] = v.y; T[kr][ns + 2] = v.z; T[kr][ns + 3] = v.w;
    }
    __syncthreads();
    #pragma unroll
    for (int i = 0; i < 4; ++i) {
        int f = t + i * 256;
        int nr = f >> 4, ks = (f & 15) * 4;
        u16 hh[4], ll[4];
        #pragma unroll
        for (int j = 0; j < 4; ++j) {
            float x = T[ks + j][nr];
            u16 hb = f2bf(x);
            hh[j] = hb;
            ll[j] = f2bf(x - bf2f(hb));
        }
        uint2 H, L;
        H.x = hh[0] | ((u32)hh[1] << 16); H.y = hh[2] | ((u32)hh[3] << 16);
        L.x = ll[0] | ((u32)ll[1] << 16); L.y = ll[2] | ((u32)ll[3] << 16);
        size_t o = (size_t)(n0 + nr) * D_MODEL + k0 + ks;
        *reinterpret_cast<uint2*>(&Ht[o]) = H;
        *reinterpret_cast<uint2*>(&Lt[o]) = L;
    }
}

// ---------------------------------------------------------------------------
// Split-bf16 MFMA GEMM: C = A @ WT^T + bias
// 128x128 tile, BK=32, 4 waves (2x2 of 64x64), 3-term split (hh + hl + lh).
// Double-buffered LDS (2 x 32 KB), prefetch distance 1: DMA for k+1 issued
// right after the consume barrier of k, in flight during compute of k.
// mode 0: fp32 out; mode 1: hi/lo bf16 out; mode 3: flat bf16 out (Ch only).
// ---------------------------------------------------------------------------
struct GArg {
    const u16* Bh; const u16* Bl; const float* bias;
    float* Cf; u16* Ch; u16* Cl; int mode;
};

__global__ __launch_bounds__(256) void gemm_split(
    const u16* __restrict__ AhG, const u16* __restrict__ AlG,
    GArg g0, GArg g1, GArg g2, int M, int N, int K)
{
    GArg ga = (blockIdx.z == 0) ? g0 : (blockIdx.z == 1) ? g1 : g2;

    __shared__ u16 AhS[2][128 * 32];
    __shared__ u16 AlS[2][128 * 32];
    __shared__ u16 BhS[2][128 * 32];
    __shared__ u16 BlS[2][128 * 32];

    const int tid  = threadIdx.x;
    const int wv   = tid >> 6;
    const int lane = tid & 63;
    const int quad = lane >> 4;
    const int l16  = lane & 15;
    const int wm   = wv >> 1, wn = wv & 1;
    const int brow = blockIdx.y * 128, bcol = blockIdx.x * 128;

    size_t aofs[2], bofs[2];
    int ldsb[2];
    #pragma unroll
    for (int j = 0; j < 2; ++j) {
        int c = wv * 2 + j;
        int r = c * 16 + (lane >> 2);
        int gseg = (lane & 3) ^ ((r >> 1) & 3);
        aofs[j] = (size_t)(brow + r) * K + gseg * 8;
        bofs[j] = (size_t)(bcol + r) * K + gseg * 8;
        ldsb[j] = c * 1024;
    }

    int aro[4], bro[4];
    #pragma unroll
    for (int i = 0; i < 4; ++i) {
        int mr = wm * 64 + i * 16 + l16;
        aro[i] = mr * 64 + ((quad ^ ((mr >> 1) & 3)) * 16);
        int nr = wn * 64 + i * 16 + l16;
        bro[i] = nr * 64 + ((quad ^ ((nr >> 1) & 3)) * 16);
    }

    f32x4 acc[4][4] = {};

    // prefetch k0 = 0 into buffer 0
    #pragma unroll
    for (int j = 0; j < 2; ++j) {
        gl16(AhG + aofs[j], (char*)AhS[0] + ldsb[j]);
        gl16(AlG + aofs[j], (char*)AlS[0] + ldsb[j]);
        gl16(ga.Bh + bofs[j], (char*)BhS[0] + ldsb[j]);
        gl16(ga.Bl + bofs[j], (char*)BlS[0] + ldsb[j]);
    }

    const int NIT = K / 32;
    for (int it = 0; it < NIT; ++it) {
        const int cur = it & 1;
        __syncthreads();   // drains vmcnt -> buf[cur] ready; prev compute done
        if (it + 1 < NIT) {
            const int k1 = (it + 1) * 32;
            const int nxt = cur ^ 1;
            #pragma unroll
            for (int j = 0; j < 2; ++j) {
                gl16(AhG + aofs[j] + k1, (char*)AhS[nxt] + ldsb[j]);
                gl16(AlG + aofs[j] + k1, (char*)AlS[nxt] + ldsb[j]);
                gl16(ga.Bh + bofs[j] + k1, (char*)BhS[nxt] + ldsb[j]);
                gl16(ga.Bl + bofs[j] + k1, (char*)BlS[nxt] + ldsb[j]);
            }
        }

        bf16x8 ah[4], al[4], bh[4], bl[4];
        #pragma unroll
        for (int i = 0; i < 4; ++i) {
            ah[i] = *reinterpret_cast<const bf16x8*>((const char*)AhS[cur] + aro[i]);
            al[i] = *reinterpret_cast<const bf16x8*>((const char*)AlS[cur] + aro[i]);
            bh[i] = *reinterpret_cast<const bf16x8*>((const char*)BhS[cur] + bro[i]);
            bl[i] = *reinterpret_cast<const bf16x8*>((const char*)BlS[cur] + bro[i]);
        }
        #pragma unroll
        for (int mi = 0; mi < 4; ++mi)
            #pragma unroll
            for (int ni = 0; ni < 4; ++ni) {
                f32x4 c = acc[mi][ni];
                c = MFMA16(ah[mi], bh[ni], c);
                c = MFMA16(ah[mi], bl[ni], c);
                c = MFMA16(al[mi], bh[ni], c);
                acc[mi][ni] = c;
            }
    }

    // epilogue
    #pragma unroll
    for (int mi = 0; mi < 4; ++mi) {
        #pragma unroll
        for (int ni = 0; ni < 4; ++ni) {
            int col = bcol + wn * 64 + ni * 16 + l16;
            float bv = ga.bias[col];
            #pragma unroll
            for (int r = 0; r < 4; ++r) {
                int row = brow + wm * 64 + mi * 16 + quad * 4 + r;
                size_t idx = (size_t)row * N + col;
                float v = acc[mi][ni][r] + bv;
                if (ga.mode == 0) {
                    ga.Cf[idx] = v;
                } else if (ga.mode == 1) {
                    u16 h = f2bf(v);
                    ga.Ch[idx] = h;
                    ga.Cl[idx] = f2bf(v - bf2f(h));
                } else {
                    ga.Ch[idx] = f2bf(v);
                }
            }
        }
    }
}

// ---------------------------------------------------------------------------
// V bf16 flat [BH][SEQ][64] (contiguous reshape slabs) -> Vt bf16 [BH][64][SEQ]
// ---------------------------------------------------------------------------
__global__ __launch_bounds__(256) void v_transpose(
    const u16* __restrict__ V, u16* __restrict__ Vt)
{
    __shared__ u16 T[64][72];
    const int bh = blockIdx.y, st = blockIdx.x;
    const u16* src = V + ((size_t)bh * SEQ + (size_t)st * 64) * 64;
    const int t = threadIdx.x;
    #pragma unroll
    for (int i = 0; i < 2; ++i) {
        int c  = t + i * 256;            // 0..511 uint4 chunks (8 u16 each)
        int s  = c >> 3;                 // 0..63
        int d0 = (c & 7) * 8;
        uint4 v = reinterpret_cast<const uint4*>(src)[c];
        u16 e[8];
        e[0] = (u16)(v.x & 0xffff); e[1] = (u16)(v.x >> 16);
        e[2] = (u16)(v.y & 0xffff); e[3] = (u16)(v.y >> 16);
        e[4] = (u16)(v.z & 0xffff); e[5] = (u16)(v.z >> 16);
        e[6] = (u16)(v.w & 0xffff); e[7] = (u16)(v.w >> 16);
        #pragma unroll
        for (int j = 0; j < 8; ++j) T[d0 + j][s] = e[j];
    }
    __syncthreads();
    const int d = t >> 2, seg = t & 3;
    u16* dst = Vt + (size_t)bh * 64 * SEQ + (size_t)d * SEQ + st * 64 + seg * 16;
    uint4 a = *reinterpret_cast<const uint4*>(&T[d][seg * 16]);
    uint4 b = *reinterpret_cast<const uint4*>(&T[d][seg * 16 + 8]);
    reinterpret_cast<uint4*>(dst)[0] = a;
    reinterpret_cast<uint4*>(dst)[1] = b;
}

// ---------------------------------------------------------------------------
// MFMA flash attention, no-max softmax, double-buffered K/V prefetch.
// grid = (16 q-tiles of 128, 32 bh), block = 256 (4 waves).
// Q fragments loaded global->VGPR directly (no Q stage, no extra barrier).
// One barrier per k-tile. LDS: 3 arrays x 2 bufs x 8KB + Pb 18KB = 66.4 KB.
// ---------------------------------------------------------------------------
__global__ __launch_bounds__(256, 2) void attn_mfma(
    const u16* __restrict__ Qh_g, const u16* __restrict__ Ql_g,
    const u16* __restrict__ Kh_g, const u16* __restrict__ Kl_g,
    const u16* __restrict__ Vt_g, u16* __restrict__ Ch_g, u16* __restrict__ Cl_g)
{
    __shared__ u16 KhS[2][64 * 64];
    __shared__ u16 KlS[2][64 * 64];
    __shared__ u16 VtS[2][64 * 64];
    __shared__ u16 Pb [128 * 72];

    const int tid  = threadIdx.x;
    const int wv   = tid >> 6;
    const int lane = tid & 63;
    const int quad = lane >> 4;
    const int l16  = lane & 15;
    const int bh   = blockIdx.y;
    const int qt   = blockIdx.x;

    const size_t qbase = ((size_t)bh * SEQ + (size_t)qt * 128) * 64;
    const size_t kbh   = (size_t)bh * SEQ * 64;
    const size_t vtbh  = (size_t)bh * 64 * SEQ;

    // ---- Q fragments: direct global -> VGPR ----
    bf16x8 qf[2][2][2];   // [sub][ks][hi/lo]
    #pragma unroll
    for (int sub = 0; sub < 2; ++sub)
        #pragma unroll
        for (int ks = 0; ks < 2; ++ks) {
            size_t o = qbase + (size_t)(wv * 32 + sub * 16 + l16) * 64 + ks * 32 + quad * 8;
            qf[sub][ks][0] = *reinterpret_cast<const bf16x8*>(Qh_g + o);
            qf[sub][ks][1] = *reinterpret_cast<const bf16x8*>(Ql_g + o);
        }

    // K/V staging addresses; chunk c = wv*2 + j (8 rows each)
    size_t kofs[2], vofs[2];
    int ldsb[2];
    #pragma unroll
    for (int j = 0; j < 2; ++j) {
        int c   = wv * 2 + j;
        int row = c * 8 + (lane >> 3);
        int sg  = (lane & 7) ^ (row & 7);
        kofs[j] = kbh  + (size_t)row * 64 + sg * 8;
        vofs[j] = vtbh + (size_t)row * SEQ + sg * 8;
        ldsb[j] = c * 1024;
    }

    // fragment LDS byte offsets: row = t*16 + l16; swizzle = (ks*4+quad)^(l16&7)
    int fro[4][2];
    #pragma unroll
    for (int t = 0; t < 4; ++t)
        #pragma unroll
        for (int ks = 0; ks < 2; ++ks)
            fro[t][ks] = (t * 16 + l16) * 128 + (((ks * 4 + quad) ^ (l16 & 7)) * 16);

    f32x4 oacc[2][4] = {};
    float psum[2][4] = {};

    // prefetch kt = 0 into buffer 0
    #pragma unroll
    for (int j = 0; j < 2; ++j) {
        gl16(Kh_g + kofs[j], (char*)KhS[0] + ldsb[j]);
        gl16(Kl_g + kofs[j], (char*)KlS[0] + ldsb[j]);
        gl16(Vt_g + vofs[j], (char*)VtS[0] + ldsb[j]);
    }

    for (int kt = 0; kt < SEQ / 64; ++kt) {
        const int cur = kt & 1;
        __syncthreads();   // drains vmcnt -> buf[cur] ready; prev compute done
        if (kt + 1 < SEQ / 64) {
            const int nxt = cur ^ 1;
            #pragma unroll
            for (int j = 0; j < 2; ++j) {
                size_t ko = kofs[j] + (size_t)(kt + 1) * 64 * 64;
                gl16(Kh_g + ko, (char*)KhS[nxt] + ldsb[j]);
                gl16(Kl_g + ko, (char*)KlS[nxt] + ldsb[j]);
                gl16(Vt_g + vofs[j] + (kt + 1) * 64, (char*)VtS[nxt] + ldsb[j]);
            }
        }

        // ---- S = Q K^T (3-term split) ----
        f32x4 sacc[2][4] = {};
        #pragma unroll
        for (int t4 = 0; t4 < 4; ++t4) {
            bf16x8 kh[2], kl[2];
            #pragma unroll
            for (int ks = 0; ks < 2; ++ks) {
                kh[ks] = *reinterpret_cast<const bf16x8*>((const char*)KhS[cur] + fro[t4][ks]);
                kl[ks] = *reinterpret_cast<const bf16x8*>((const char*)KlS[cur] + fro[t4][ks]);
            }
            #pragma unroll
            for (int sub = 0; sub < 2; ++sub) {
                f32x4 a = sacc[sub][t4];
                a = MFMA16(qf[sub][0][0], kh[0], a);
                a = MFMA16(qf[sub][0][0], kl[0], a);
                a = MFMA16(qf[sub][0][1], kh[0], a);
                a = MFMA16(qf[sub][1][0], kh[1], a);
                a = MFMA16(qf[sub][1][0], kl[1], a);
                a = MFMA16(qf[sub][1][1], kh[1], a);
                sacc[sub][t4] = a;
            }
        }

        // ---- p = exp(s/8 - 11.09); uniform shift cancels in normalization ----
        #pragma unroll
        for (int sub = 0; sub < 2; ++sub) {
            int rowb = wv * 32 + sub * 16 + quad * 4;
            #pragma unroll
            for (int r = 0; r < 4; ++r) {
                float p0 = __expf(fmaf(sacc[sub][0][r], 0.125f, -11.0903549f));
                float p1 = __expf(fmaf(sacc[sub][1][r], 0.125f, -11.0903549f));
                float p2 = __expf(fmaf(sacc[sub][2][r], 0.125f, -11.0903549f));
                float p3 = __expf(fmaf(sacc[sub][3][r], 0.125f, -11.0903549f));
                psum[sub][r] += (p0 + p1) + (p2 + p3);
                int ro = (rowb + r) * 72 + l16;
                Pb[ro +  0] = f2bf(p0);
                Pb[ro + 16] = f2bf(p1);
                Pb[ro + 32] = f2bf(p2);
                Pb[ro + 48] = f2bf(p3);
            }
        }
        // Pb rows are wave-private: lgkmcnt ordering only, no barrier.

        // ---- O += P @ V ----
        #pragma unroll
        for (int sub = 0; sub < 2; ++sub) {
            bf16x8 ap[2];
            #pragma unroll
            for (int ks = 0; ks < 2; ++ks)
                ap[ks] = *reinterpret_cast<const bf16x8*>(
                    &Pb[(wv * 32 + sub * 16 + l16) * 72 + ks * 32 + quad * 8]);
            #pragma unroll
            for (int dt = 0; dt < 4; ++dt) {
                #pragma unroll
                for (int ks = 0; ks < 2; ++ks) {
                    bf16x8 bv = *reinterpret_cast<const bf16x8*>((const char*)VtS[cur] + fro[dt][ks]);
                    oacc[sub][dt] = MFMA16(ap[ks], bv, oacc[sub][dt]);
                }
            }
        }
    }

    // ---- row-sum reduction across the 16 k-lanes (once) ----
    #pragma unroll
    for (int sub = 0; sub < 2; ++sub)
        #pragma unroll
        for (int r = 0; r < 4; ++r) {
            float s = psum[sub][r];
            s += __shfl_xor(s, 1, 64);
            s += __shfl_xor(s, 2, 64);
            s += __shfl_xor(s, 4, 64);
            s += __shfl_xor(s, 8, 64);
            psum[sub][r] = s;
        }

    // ---- epilogue: normalize, split to hi/lo bf16 ctx ----
    u16* Oh = Ch_g + qbase;
    u16* Ol = Cl_g + qbase;
    #pragma unroll
    for (int sub = 0; sub < 2; ++sub) {
        float inv[4];
        #pragma unroll
        for (int r = 0; r < 4; ++r) inv[r] = 1.0f / psum[sub][r];
        #pragma unroll
        for (int dt = 0; dt < 4; ++dt)
            #pragma unroll
            for (int r = 0; r < 4; ++r) {
                int row = wv * 32 + sub * 16 + quad * 4 + r;
                float v = oacc[sub][dt][r] * inv[r];
                u16 h = f2bf(v);
                size_t idx = (size_t)row * 64 + dt * 16 + l16;
                Oh[idx] = h;
                Ol[idx] = f2bf(v - bf2f(h));
            }
    }
}

// ---------------------------------------------------------------------------
extern "C" void kernel_launch(void* const* d_in, const int* in_sizes, int n_in,
                              void* d_out, int out_size, void* d_ws, size_t ws_size,
                              hipStream_t stream)
{
    const float* x  = (const float*)d_in[0];
    const float* Wq = (const float*)d_in[1];
    const float* bq = (const float*)d_in[2];
    const float* Wk = (const float*)d_in[3];
    const float* bk = (const float*)d_in[4];
    const float* Wv = (const float*)d_in[5];
    const float* bv = (const float*)d_in[6];
    const float* Wo = (const float*)d_in[7];
    const float* bo = (const float*)d_in[8];
    float* out = (float*)d_out;

    const int M = BATCH * SEQ;        // 4096
    const int N = D_MODEL;            // 1024
    const int K = D_MODEL;            // 1024
    const size_t NE = (size_t)M * N;  // 4,194,304
    const size_t NW = (size_t)N * K;  // 1,048,576

    u16* w16 = (u16*)d_ws;
    u16* Xh   = w16;
    u16* Xl   = Xh   + NE;
    u16* Qh   = Xl   + NE;
    u16* Ql   = Qh   + NE;
    u16* Kh   = Ql   + NE;
    u16* Kl   = Kh   + NE;
    u16* Ctxh = Kl   + NE;
    u16* Ctxl = Ctxh + NE;
    u16* Vtb  = Ctxl + NE;
    u16* Vb16 = Vtb  + NE;
    u16* WTqh = Vb16 + NE;
    u16* WTql = WTqh + NW;
    u16* WTkh = WTql + NW;
    u16* WTkl = WTkh + NW;
    u16* WTvh = WTkl + NW;
    u16* WTvl = WTvh + NW;
    u16* WToh = WTvl + NW;
    u16* WTol = WToh + NW;

    dim3 blk(256);

    // input conversions
    hilo_conv<<<dim3((int)(NE / 4 / 256)), blk, 0, stream>>>(x, Xh, Xl, (int)(NE / 4));
    wt_conv<<<dim3(16, 16, 4), blk, 0, stream>>>(
        Wq, Wk, Wv, Wo, WTqh, WTql, WTkh, WTkl, WTvh, WTvl, WToh, WTol);

    // QKV projections: Q,K -> hi/lo bf16; V -> flat bf16
    GArg aq = {WTqh, WTql, bq, nullptr, Qh, Ql, 1};
    GArg ak = {WTkh, WTkl, bk, nullptr, Kh, Kl, 1};
    GArg av = {WTvh, WTvl, bv, nullptr, Vb16, nullptr, 3};
    gemm_split<<<dim3(N / 128, M / 128, 3), blk, 0, stream>>>(Xh, Xl, aq, ak, av, M, N, K);

    // transpose V per contiguous reshape slab (bf16 in, bf16 out)
    v_transpose<<<dim3(SEQ / 64, BH), blk, 0, stream>>>(Vb16, Vtb);

    // attention -> ctx hi/lo
    attn_mfma<<<dim3(SEQ / 128, BH), blk, 0, stream>>>(Qh, Ql, Kh, Kl, Vtb, Ctxh, Ctxl);

    // output projection
    GArg ao = {WToh, WTol, bo, out, nullptr, nullptr, 0};
    gemm_split<<<dim3(N / 128, M / 128, 1), blk, 0, stream>>>(Ctxh, Ctxl, ao, ao, ao, M, N, K);
}